// Round 9
// baseline (437.770 us; speedup 1.0000x reference)
//
#include <hip/hip_runtime.h>
#include <stdint.h>

#define COLS 65536
#define KSEL 32
#define TPB 256
#define CAP 1024
#define PIV_HI 0xC0300000u   /* flip32(2.75f); rank-32/65536 threshold for N(0,1) ~ 3.30 */

typedef __attribute__((ext_vector_type(4))) float f32x4;

__device__ __forceinline__ uint32_t flip32(float f) {
    uint32_t u = __float_as_uint(f);
    return u ^ ((u & 0x80000000u) ? 0xFFFFFFFFu : 0x80000000u);
}
__device__ __forceinline__ float unflip32(uint32_t k) {
    uint32_t u = k ^ ((k & 0x80000000u) ? 0x80000000u : 0xFFFFFFFFu);
    return __uint_as_float(u);
}

// One block per row, copy-shaped main loop (m13 pattern: every iteration issues one NT
// load of x and one NT zero-store of out — steady 1:1 read/write mix device-wide,
// instead of round-5's phase-bulk read-then-write):
//   (1) interleaved: NT-load x[j] + NT-store 0 -> out[j] + rare candidate capture to LDS
//   (2) __syncthreads (drains vmcnt -> all zeros retired, cand[] visible)
//   (3) per-wave redundant bisection over LDS candidates (shfl-only, no barriers)
//   (4) scatter the 32 winners (no wait needed; zeros drained at the barrier)
// Key = (flip32(v) << 32) | (0xFFFF - col): strict monotone in (value desc, col asc) ->
// distinct keys, exact rank-32 boundary exists, matches jax.lax.top_k tie order.
__global__ __launch_bounds__(TPB)
void topk_onepass_kernel(const float* __restrict__ x, float* __restrict__ out) {
    __shared__ unsigned long long cand[CAP];   // 8 KiB
    __shared__ int s_cnt;

    const int row  = blockIdx.x;
    const int tid  = threadIdx.x;
    const int lane = tid & 63;

    if (tid == 0) s_cnt = 0;
    __syncthreads();

    const f32x4* __restrict__ xv = (const f32x4*)(x + (size_t)row * COLS);
    float* __restrict__ orow = out + (size_t)row * COLS;
    f32x4* __restrict__ ov = (f32x4*)orow;
    const f32x4 z = (f32x4)(0.f);

    // ---- Phase 1: copy-shaped stream — load x, store zeros, filter candidates.
    #pragma unroll 8
    for (int j = 0; j < COLS / 4 / TPB; ++j) {           // 64 iters, fully coalesced
        const int vi = j * TPB + tid;
        const f32x4 v = __builtin_nontemporal_load(&xv[vi]);
        __builtin_nontemporal_store(z, &ov[vi]);
        const uint32_t f0 = flip32(v.x), f1 = flip32(v.y), f2 = flip32(v.z), f3 = flip32(v.w);
        const int n = (int)(f0 >= PIV_HI) + (int)(f1 >= PIV_HI)
                    + (int)(f2 >= PIV_HI) + (int)(f3 >= PIV_HI);
        if (n) {                                         // ~1.2% of lane-iterations
            int pos = atomicAdd(&s_cnt, n);              // LDS atomic, uncontended
            const uint32_t col0 = (uint32_t)vi << 2;
            const uint32_t fs[4] = {f0, f1, f2, f3};
            #pragma unroll
            for (int e = 0; e < 4; ++e) {
                if (fs[e] >= PIV_HI) {
                    if (pos < CAP)
                        cand[pos] = ((unsigned long long)fs[e] << 32)
                                  | (unsigned long long)(0xFFFFu - (col0 + e));
                    ++pos;
                }
            }
        }
    }
    __syncthreads();                                     // drains loads AND zero-stores
    const int c = s_cnt;

    if (c >= KSEL && c <= CAP) {
        // ---- Phase 2: per-wave redundant bisection counting from LDS.
        unsigned long long lo = ((unsigned long long)PIV_HI << 32) - 1ull;  // count(>lo)==c
        unsigned long long hi = ~0ull;
        unsigned long long mid = lo;
        int m = c;
        for (int it = 0; it < 72 && m != KSEL; ++it) {
            mid = lo + ((hi - lo) >> 1);
            int local = 0;
            #pragma unroll
            for (int i = 0; i < 16; ++i) {
                const int idx = i * 64 + lane;
                local += (int)(idx < c && cand[idx] > mid);
            }
            #pragma unroll
            for (int off = 32; off >= 1; off >>= 1) local += __shfl_xor(local, off, 64);
            m = local;
            if (m > KSEL) lo = mid; else if (m < KSEL) hi = mid;
        }

        // ---- Phase 3: scatter winners (zeros already drained at the barrier).
        for (int idx = tid; idx < c; idx += TPB) {       // each candidate handled once
            const unsigned long long key = cand[idx];
            if (key > mid) {
                const uint32_t col = 0xFFFFu - (uint32_t)(key & 0xFFFFull);
                orow[col] = fmaxf(unflip32((uint32_t)(key >> 32)), 0.f);
            }
        }
    } else {
        // Correctness fallback (P ~ 0 for N(0,1)): wave-redundant full-row bisection from
        // global, then scatter (zeros already written by phase 1).
        const float* __restrict__ xr = x + (size_t)row * COLS;
        unsigned long long lo = 0ull, hi = ~0ull, mid = 0ull;
        int m = -1;
        for (int it = 0; it < 96 && m != KSEL; ++it) {
            mid = lo + ((hi - lo) >> 1);
            int local = 0;
            for (int j = lane; j < COLS; j += 64) {
                const unsigned long long key =
                    ((unsigned long long)flip32(xr[j]) << 32)
                    | (unsigned long long)(0xFFFFu - (uint32_t)j);
                local += (int)(key > mid);
            }
            #pragma unroll
            for (int off = 32; off >= 1; off >>= 1) local += __shfl_xor(local, off, 64);
            m = local;
            if (m > KSEL) lo = mid; else if (m < KSEL) hi = mid;
        }
        const int wave = tid >> 6;
        const uint32_t segLo = (uint32_t)wave * 16384u, segHi = segLo + 16384u;
        for (uint32_t j = segLo + lane; j < segHi; j += 64) {
            const float v = xr[j];
            const unsigned long long key =
                ((unsigned long long)flip32(v) << 32)
                | (unsigned long long)(0xFFFFu - j);
            if (key > mid) orow[j] = fmaxf(v, 0.f);
        }
    }
}

extern "C" void kernel_launch(void* const* d_in, const int* in_sizes, int n_in,
                              void* d_out, int out_size, void* d_ws, size_t ws_size,
                              hipStream_t stream) {
    const float* x = (const float*)d_in[0];
    float* out = (float*)d_out;
    const int rows = in_sizes[0] / COLS;
    topk_onepass_kernel<<<rows, TPB, 0, stream>>>(x, out);
}

// Round 10
// 419.151 us; speedup vs baseline: 1.0444x; 1.0444x over previous
//
#include <hip/hip_runtime.h>
#include <stdint.h>

#define COLS 65536
#define KSEL 32
#define TPB 256
#define CAP 1024
#define PIV_HI 0xC0300000u   /* flip32(2.75f); rank-32/65536 threshold for N(0,1) ~ 3.30 */

typedef __attribute__((ext_vector_type(4))) float f32x4;

__device__ __forceinline__ uint32_t flip32(float f) {
    uint32_t u = __float_as_uint(f);
    return u ^ ((u & 0x80000000u) ? 0xFFFFFFFFu : 0x80000000u);
}
__device__ __forceinline__ float unflip32(uint32_t k) {
    uint32_t u = k ^ ((k & 0x80000000u) ? 0x80000000u : 0xFFFFFFFFu);
    return __uint_as_float(u);
}

// One block per row. R5 structure with BLOCK-PARITY phase stagger:
//   even blocks: NT read+filter -> NT zero burst -> bisect (drain overlaps) -> vmcnt(0) -> scatter
//   odd  blocks: NT zero burst -> NT read+filter (first load-wait drains stores) -> bisect -> scatter
// Rationale: vmcnt retires in issue order, so per-WAVE read/write interleave serializes
// (R6/R9 lessons). Per-BLOCK stagger gives the device a steady ~1:1 read/write mix
// (m13's copy condition) without any intra-wave serialization beyond what each phase
// order already pays. Key = (flip32(v)<<32) | (0xFFFF-col): strict monotone in
// (value desc, col asc), distinct keys, exact rank-32 boundary, jax.lax.top_k tie order.
__global__ __launch_bounds__(TPB)
void topk_onepass_kernel(const float* __restrict__ x, float* __restrict__ out) {
    __shared__ unsigned long long cand[CAP];   // 8 KiB
    __shared__ int s_cnt;

    const int row  = blockIdx.x;
    const int tid  = threadIdx.x;
    const int lane = tid & 63;
    const int wave = tid >> 6;
    const bool writeFirst = (blockIdx.x & 1) != 0;

    if (tid == 0) s_cnt = 0;
    __syncthreads();

    const f32x4* __restrict__ xv = (const f32x4*)(x + (size_t)row * COLS);
    float* __restrict__ orow = out + (size_t)row * COLS;
    f32x4* __restrict__ ov = (f32x4*)orow;
    const f32x4 z = (f32x4)(0.f);

    const int segBase4 = wave * 4096;                    // this wave's quarter (float4 units)
    const uint32_t segLo = (uint32_t)wave * 16384u, segHi = segLo + 16384u;

    // ---- Odd blocks: zero-store burst first (drains under the read phase device-wide).
    if (writeFirst) {
        #pragma unroll
        for (int i = 0; i < 64; ++i)
            __builtin_nontemporal_store(z, &ov[segBase4 + i * 64 + lane]);
    }

    // ---- Read phase: NT stream + rare candidate capture into LDS.
    #pragma unroll 8
    for (int j = 0; j < COLS / 4 / TPB; ++j) {           // 64 coalesced float4 iters
        const int vi = j * TPB + tid;
        const f32x4 v = __builtin_nontemporal_load(&xv[vi]);
        const uint32_t f0 = flip32(v.x), f1 = flip32(v.y), f2 = flip32(v.z), f3 = flip32(v.w);
        const int n = (int)(f0 >= PIV_HI) + (int)(f1 >= PIV_HI)
                    + (int)(f2 >= PIV_HI) + (int)(f3 >= PIV_HI);
        if (n) {                                         // ~1.2% of lane-iterations
            int pos = atomicAdd(&s_cnt, n);              // LDS atomic, uncontended
            const uint32_t col0 = (uint32_t)vi << 2;
            const uint32_t fs[4] = {f0, f1, f2, f3};
            #pragma unroll
            for (int e = 0; e < 4; ++e) {
                if (fs[e] >= PIV_HI) {
                    if (pos < CAP)
                        cand[pos] = ((unsigned long long)fs[e] << 32)
                                  | (unsigned long long)(0xFFFFu - (col0 + e));
                    ++pos;
                }
            }
        }
    }
    __syncthreads();
    const int c = s_cnt;

    if (c >= KSEL && c <= CAP) {
        // ---- Even blocks: zero burst now; drains under the bisection.
        if (!writeFirst) {
            #pragma unroll
            for (int i = 0; i < 64; ++i)
                __builtin_nontemporal_store(z, &ov[segBase4 + i * 64 + lane]);
        }

        // ---- Per-wave redundant bisection counting from LDS (shfl-only).
        unsigned long long lo = ((unsigned long long)PIV_HI << 32) - 1ull;  // count(>lo)==c
        unsigned long long hi = ~0ull;
        unsigned long long mid = lo;
        int m = c;
        for (int it = 0; it < 72 && m != KSEL; ++it) {
            mid = lo + ((hi - lo) >> 1);
            int local = 0;
            #pragma unroll
            for (int i = 0; i < 16; ++i) {
                const int idx = i * 64 + lane;
                local += (int)(idx < c && cand[idx] > mid);
            }
            #pragma unroll
            for (int off = 32; off >= 1; off >>= 1) local += __shfl_xor(local, off, 64);
            m = local;
            if (m > KSEL) lo = mid; else if (m < KSEL) hi = mid;
        }

        // ---- Scatter winners in my quarter. Even blocks must drain their zero burst;
        //      odd blocks' zeros retired long ago (forced by the read phase's waits).
        if (!writeFirst)
            asm volatile("s_waitcnt vmcnt(0)" ::: "memory");
        for (int idx = lane; idx < c; idx += 64) {
            const unsigned long long key = cand[idx];
            if (key > mid) {
                const uint32_t col = 0xFFFFu - (uint32_t)(key & 0xFFFFull);
                if (col >= segLo && col < segHi)
                    orow[col] = fmaxf(unflip32((uint32_t)(key >> 32)), 0.f);
            }
        }
    } else {
        // Correctness fallback (P ~ 0 for N(0,1)): wave-redundant full-row bisection from
        // global, then zero-fill (if not already done) + scatter over my quarter.
        const float* __restrict__ xr = x + (size_t)row * COLS;
        unsigned long long lo = 0ull, hi = ~0ull, mid = 0ull;
        int m = -1;
        for (int it = 0; it < 96 && m != KSEL; ++it) {
            mid = lo + ((hi - lo) >> 1);
            int local = 0;
            for (int j = lane; j < COLS; j += 64) {
                const unsigned long long key =
                    ((unsigned long long)flip32(xr[j]) << 32)
                    | (unsigned long long)(0xFFFFu - (uint32_t)j);
                local += (int)(key > mid);
            }
            #pragma unroll
            for (int off = 32; off >= 1; off >>= 1) local += __shfl_xor(local, off, 64);
            m = local;
            if (m > KSEL) lo = mid; else if (m < KSEL) hi = mid;
        }
        if (!writeFirst) {
            #pragma unroll
            for (int i = 0; i < 64; ++i)
                __builtin_nontemporal_store(z, &ov[segBase4 + i * 64 + lane]);
        }
        asm volatile("s_waitcnt vmcnt(0)" ::: "memory");
        for (uint32_t j = segLo + lane; j < segHi; j += 64) {
            const float v = xr[j];
            const unsigned long long key =
                ((unsigned long long)flip32(v) << 32)
                | (unsigned long long)(0xFFFFu - j);
            if (key > mid) orow[j] = fmaxf(v, 0.f);
        }
    }
}

extern "C" void kernel_launch(void* const* d_in, const int* in_sizes, int n_in,
                              void* d_out, int out_size, void* d_ws, size_t ws_size,
                              hipStream_t stream) {
    const float* x = (const float*)d_in[0];
    float* out = (float*)d_out;
    const int rows = in_sizes[0] / COLS;
    topk_onepass_kernel<<<rows, TPB, 0, stream>>>(x, out);
}

// Round 11
// 405.838 us; speedup vs baseline: 1.0787x; 1.0328x over previous
//
#include <hip/hip_runtime.h>
#include <stdint.h>

#define COLS 65536
#define KSEL 32
#define TPB 256
#define CAP 1024
#define NWIN 64
#define PIV_HI 0xC0300000u   /* flip32(2.75f); rank-32/65536 threshold for N(0,1) ~ 3.30 */

typedef __attribute__((ext_vector_type(4))) float f32x4;
typedef __attribute__((ext_vector_type(4))) unsigned int u32x4;

__device__ __forceinline__ uint32_t flip32(float f) {
    uint32_t u = __float_as_uint(f);
    return u ^ ((u & 0x80000000u) ? 0xFFFFFFFFu : 0x80000000u);
}
__device__ __forceinline__ float unflip32(uint32_t k) {
    uint32_t u = k ^ ((k & 0x80000000u) ? 0x80000000u : 0xFFFFFFFFu);
    return __uint_as_float(u);
}

// One block per row. R5 structure, but the write path is a SINGLE patched NT store pass:
//   (1) NT read stream + rare candidate capture into LDS (~195 of 65536)   [= R5]
//   (2) per-wave redundant bisection from LDS (shfl-only)                   [= R5]
//   (3) extract the 32 winners -> LDS (col,val) table + 65536-bit LDS bitmap
//   (4) one NT store pass writes the FINAL row: zeros, patched with winner values where
//       the bitmap says so. No zero-burst->vmcnt(0)->scatter ordering stall (R5's last
//       structural serialization), no second store pass. Block ends with stores in flight.
// Key = (flip32(v)<<32) | (0xFFFF-col): strict monotone in (value desc, col asc) ->
// distinct keys, exact rank-32 boundary, matches jax.lax.top_k tie order.
__global__ __launch_bounds__(TPB)
void topk_onepass_kernel(const float* __restrict__ x, float* __restrict__ out) {
    __shared__ unsigned long long cand[CAP];   // 8 KiB
    __shared__ uint32_t bitmap[COLS / 32];     // 8 KiB, 1 bit per column
    __shared__ uint32_t winc[NWIN];
    __shared__ float    winv[NWIN];
    __shared__ int s_cnt, s_nwin;

    const int row  = blockIdx.x;
    const int tid  = threadIdx.x;
    const int lane = tid & 63;

    if (tid == 0) { s_cnt = 0; s_nwin = 0; }
    // clear bitmap: 512 uint4 / 256 threads = 2 per thread
    {
        const u32x4 z4 = (u32x4)(0u);
        ((u32x4*)bitmap)[tid]       = z4;
        ((u32x4*)bitmap)[tid + TPB] = z4;
    }
    __syncthreads();

    const f32x4* __restrict__ xv = (const f32x4*)(x + (size_t)row * COLS);
    float* __restrict__ orow = out + (size_t)row * COLS;
    f32x4* __restrict__ ov = (f32x4*)orow;
    const f32x4 z = (f32x4)(0.f);

    // ---- Phase 1: NT read stream + rare candidate capture into LDS.
    #pragma unroll 8
    for (int j = 0; j < COLS / 4 / TPB; ++j) {           // 64 coalesced float4 iters
        const int vi = j * TPB + tid;
        const f32x4 v = __builtin_nontemporal_load(&xv[vi]);
        const uint32_t f0 = flip32(v.x), f1 = flip32(v.y), f2 = flip32(v.z), f3 = flip32(v.w);
        const int n = (int)(f0 >= PIV_HI) + (int)(f1 >= PIV_HI)
                    + (int)(f2 >= PIV_HI) + (int)(f3 >= PIV_HI);
        if (n) {                                         // ~1.2% of lane-iterations
            int pos = atomicAdd(&s_cnt, n);              // LDS atomic, uncontended
            const uint32_t col0 = (uint32_t)vi << 2;
            const uint32_t fs[4] = {f0, f1, f2, f3};
            #pragma unroll
            for (int e = 0; e < 4; ++e) {
                if (fs[e] >= PIV_HI) {
                    if (pos < CAP)
                        cand[pos] = ((unsigned long long)fs[e] << 32)
                                  | (unsigned long long)(0xFFFFu - (col0 + e));
                    ++pos;
                }
            }
        }
    }
    __syncthreads();
    const int c = s_cnt;

    if (c >= KSEL && c <= CAP) {
        // ---- Phase 2: per-wave redundant bisection counting from LDS (shfl-only).
        unsigned long long lo = ((unsigned long long)PIV_HI << 32) - 1ull;  // count(>lo)==c
        unsigned long long hi = ~0ull;
        unsigned long long mid = lo;
        int m = c;
        for (int it = 0; it < 72 && m != KSEL; ++it) {
            mid = lo + ((hi - lo) >> 1);
            int local = 0;
            #pragma unroll
            for (int i = 0; i < 16; ++i) {
                const int idx = i * 64 + lane;
                local += (int)(idx < c && cand[idx] > mid);
            }
            #pragma unroll
            for (int off = 32; off >= 1; off >>= 1) local += __shfl_xor(local, off, 64);
            m = local;
            if (m > KSEL) lo = mid; else if (m < KSEL) hi = mid;
        }

        // ---- Phase 3: extract winners -> (col,val) table + bitmap. Each thread owns
        //      cand[tid + q*TPB], so every winner is appended exactly once.
        #pragma unroll
        for (int q = 0; q < CAP / TPB; ++q) {
            const int idx = q * TPB + tid;
            if (idx < c) {
                const unsigned long long key = cand[idx];
                if (key > mid) {
                    const int pos = atomicAdd(&s_nwin, 1);
                    if (pos < NWIN) {
                        const uint32_t col = 0xFFFFu - (uint32_t)(key & 0xFFFFull);
                        winc[pos] = col;
                        winv[pos] = fmaxf(unflip32((uint32_t)(key >> 32)), 0.f);
                        atomicOr(&bitmap[col >> 5], 1u << (col & 31u));
                    }
                }
            }
        }
    } else {
        // Correctness fallback (P ~ 0 for N(0,1)): wave-redundant full-row bisection from
        // global, then block-wide winner extraction (each col visited once).
        const float* __restrict__ xr = x + (size_t)row * COLS;
        unsigned long long lo = 0ull, hi = ~0ull, mid = 0ull;
        int m = -1;
        for (int it = 0; it < 96 && m != KSEL; ++it) {
            mid = lo + ((hi - lo) >> 1);
            int local = 0;
            for (int j = lane; j < COLS; j += 64) {
                const unsigned long long key =
                    ((unsigned long long)flip32(xr[j]) << 32)
                    | (unsigned long long)(0xFFFFu - (uint32_t)j);
                local += (int)(key > mid);
            }
            #pragma unroll
            for (int off = 32; off >= 1; off >>= 1) local += __shfl_xor(local, off, 64);
            m = local;
            if (m > KSEL) lo = mid; else if (m < KSEL) hi = mid;
        }
        for (int j = tid; j < COLS; j += TPB) {
            const float v = xr[j];
            const unsigned long long key =
                ((unsigned long long)flip32(v) << 32)
                | (unsigned long long)(0xFFFFu - (uint32_t)j);
            if (key > mid) {
                const int pos = atomicAdd(&s_nwin, 1);
                if (pos < NWIN) {
                    winc[pos] = (uint32_t)j;
                    winv[pos] = fmaxf(v, 0.f);
                    atomicOr(&bitmap[(uint32_t)j >> 5], 1u << ((uint32_t)j & 31u));
                }
            }
        }
    }
    __syncthreads();                                     // winners + bitmap visible
    const int nw = (s_nwin < NWIN) ? s_nwin : NWIN;

    // ---- Phase 4: single patched NT store pass — final data in one stream, no ordering
    //      stall, no scatter pass. Bitmap read: 8 unique words/wave-iter -> conflict-free.
    #pragma unroll 8
    for (int j = 0; j < COLS / 4 / TPB; ++j) {
        const int vi = j * TPB + tid;
        const uint32_t col0 = (uint32_t)vi << 2;
        const uint32_t nib = (bitmap[col0 >> 5] >> (col0 & 31u)) & 0xFu;
        f32x4 w = z;
        if (nib) {                                       // ~0.2% of lane-iterations
            #pragma unroll
            for (int e = 0; e < 4; ++e) {
                if ((nib >> e) & 1u) {
                    const uint32_t col = col0 + e;
                    for (int t = 0; t < nw; ++t)
                        if (winc[t] == col) { w[e] = winv[t]; break; }
                }
            }
        }
        __builtin_nontemporal_store(w, &ov[vi]);
    }
}

extern "C" void kernel_launch(void* const* d_in, const int* in_sizes, int n_in,
                              void* d_out, int out_size, void* d_ws, size_t ws_size,
                              hipStream_t stream) {
    const float* x = (const float*)d_in[0];
    float* out = (float*)d_out;
    const int rows = in_sizes[0] / COLS;
    topk_onepass_kernel<<<rows, TPB, 0, stream>>>(x, out);
}

// Round 12
// 394.989 us; speedup vs baseline: 1.1083x; 1.0275x over previous
//
#include <hip/hip_runtime.h>
#include <stdint.h>

#define COLS 65536
#define KSEL 32
#define TPB 256
#define CAP 1024
#define PIV_HI 0xC0300000u   /* flip32(2.75f); rank-32/65536 threshold for N(0,1) ~ 3.30 */

typedef __attribute__((ext_vector_type(4))) float f32x4;

__device__ __forceinline__ uint32_t flip32(float f) {
    uint32_t u = __float_as_uint(f);
    return u ^ ((u & 0x80000000u) ? 0xFFFFFFFFu : 0x80000000u);
}
__device__ __forceinline__ float unflip32(uint32_t k) {
    uint32_t u = k ^ ((k & 0x80000000u) ? 0x80000000u : 0xFFFFFFFFu);
    return __uint_as_float(u);
}

// Channel-split design:
//   Dispatch 1: hipMemsetAsync(d_out, 0) -> vendor rocclr fill, measured 6.5-6.7 TB/s
//               (fastest store stream on this chip; our NT fill only reached ~5.3).
//   Dispatch 2 (this kernel, one block per row): PURE READ stream + tiny scatter.
//     (1) NT read + rare candidate capture into LDS (~195 of 65536)
//     (2) per-wave redundant bisection from LDS (shfl-only, no barriers)
//     (3) scatter the 32 winners directly (output pre-zeroed; 128 B/row of writes)
// Each dispatch runs its pure stream at max BW; floor = bytes/BW with no mixing penalty.
// Key = (flip32(v)<<32) | (0xFFFF-col): strict monotone in (value desc, col asc) ->
// distinct keys, exact rank-32 boundary, matches jax.lax.top_k tie order.
__global__ __launch_bounds__(TPB)
void topk_collect_scatter_kernel(const float* __restrict__ x, float* __restrict__ out) {
    __shared__ unsigned long long cand[CAP];   // 8 KiB
    __shared__ int s_cnt;

    const int row  = blockIdx.x;
    const int tid  = threadIdx.x;
    const int lane = tid & 63;

    if (tid == 0) s_cnt = 0;
    __syncthreads();

    const f32x4* __restrict__ xv = (const f32x4*)(x + (size_t)row * COLS);
    float* __restrict__ orow = out + (size_t)row * COLS;

    // ---- Phase 1: NT read stream + rare candidate capture into LDS.
    #pragma unroll 8
    for (int j = 0; j < COLS / 4 / TPB; ++j) {           // 64 coalesced float4 iters
        const int vi = j * TPB + tid;
        const f32x4 v = __builtin_nontemporal_load(&xv[vi]);
        const uint32_t f0 = flip32(v.x), f1 = flip32(v.y), f2 = flip32(v.z), f3 = flip32(v.w);
        const int n = (int)(f0 >= PIV_HI) + (int)(f1 >= PIV_HI)
                    + (int)(f2 >= PIV_HI) + (int)(f3 >= PIV_HI);
        if (n) {                                         // ~1.2% of lane-iterations
            int pos = atomicAdd(&s_cnt, n);              // LDS atomic, uncontended
            const uint32_t col0 = (uint32_t)vi << 2;
            const uint32_t fs[4] = {f0, f1, f2, f3};
            #pragma unroll
            for (int e = 0; e < 4; ++e) {
                if (fs[e] >= PIV_HI) {
                    if (pos < CAP)
                        cand[pos] = ((unsigned long long)fs[e] << 32)
                                  | (unsigned long long)(0xFFFFu - (col0 + e));
                    ++pos;
                }
            }
        }
    }
    __syncthreads();
    const int c = s_cnt;

    if (c >= KSEL && c <= CAP) {
        // ---- Phase 2: per-wave redundant bisection counting from LDS (shfl-only).
        unsigned long long lo = ((unsigned long long)PIV_HI << 32) - 1ull;  // count(>lo)==c
        unsigned long long hi = ~0ull;
        unsigned long long mid = lo;
        int m = c;
        for (int it = 0; it < 72 && m != KSEL; ++it) {
            mid = lo + ((hi - lo) >> 1);
            int local = 0;
            #pragma unroll
            for (int i = 0; i < 16; ++i) {
                const int idx = i * 64 + lane;
                local += (int)(idx < c && cand[idx] > mid);
            }
            #pragma unroll
            for (int off = 32; off >= 1; off >>= 1) local += __shfl_xor(local, off, 64);
            m = local;
            if (m > KSEL) lo = mid; else if (m < KSEL) hi = mid;
        }

        // ---- Phase 3: scatter the 32 winners (out pre-zeroed by the memset dispatch).
        for (int idx = tid; idx < c; idx += TPB) {       // each candidate handled once
            const unsigned long long key = cand[idx];
            if (key > mid) {
                const uint32_t col = 0xFFFFu - (uint32_t)(key & 0xFFFFull);
                orow[col] = fmaxf(unflip32((uint32_t)(key >> 32)), 0.f);
            }
        }
    } else {
        // Correctness fallback (P ~ 0 for N(0,1)): wave-redundant full-row bisection from
        // global, then scatter (output pre-zeroed by the memset dispatch).
        const float* __restrict__ xr = x + (size_t)row * COLS;
        unsigned long long lo = 0ull, hi = ~0ull, mid = 0ull;
        int m = -1;
        for (int it = 0; it < 96 && m != KSEL; ++it) {
            mid = lo + ((hi - lo) >> 1);
            int local = 0;
            for (int j = lane; j < COLS; j += 64) {
                const unsigned long long key =
                    ((unsigned long long)flip32(xr[j]) << 32)
                    | (unsigned long long)(0xFFFFu - (uint32_t)j);
                local += (int)(key > mid);
            }
            #pragma unroll
            for (int off = 32; off >= 1; off >>= 1) local += __shfl_xor(local, off, 64);
            m = local;
            if (m > KSEL) lo = mid; else if (m < KSEL) hi = mid;
        }
        for (int j = tid; j < COLS; j += TPB) {
            const float v = xr[j];
            const unsigned long long key =
                ((unsigned long long)flip32(v) << 32)
                | (unsigned long long)(0xFFFFu - (uint32_t)j);
            if (key > mid) orow[j] = fmaxf(v, 0.f);
        }
    }
}

extern "C" void kernel_launch(void* const* d_in, const int* in_sizes, int n_in,
                              void* d_out, int out_size, void* d_ws, size_t ws_size,
                              hipStream_t stream) {
    const float* x = (const float*)d_in[0];
    float* out = (float*)d_out;
    const int rows = in_sizes[0] / COLS;
    // Write channel: vendor fill (6.5-6.7 TB/s measured on this chip).
    hipMemsetAsync(d_out, 0, (size_t)out_size * sizeof(float), stream);
    // Read channel: pure streaming collect + select + 32-element scatter per row.
    topk_collect_scatter_kernel<<<rows, TPB, 0, stream>>>(x, out);
}